// Round 14
// baseline (239.503 us; speedup 1.0000x reference)
//
#include <hip/hip_runtime.h>
#include <hip/hip_bf16.h>

typedef __attribute__((ext_vector_type(8))) short short8;
typedef __attribute__((ext_vector_type(4))) float f32x4;
typedef __hip_bfloat16 bf16;

typedef const void __attribute__((address_space(1))) as1_const_void;
typedef void __attribute__((address_space(3))) as3_void;

static __device__ __forceinline__ void gload_lds16(const bf16* g, bf16* l) {
    __builtin_amdgcn_global_load_lds((as1_const_void*)g, (as3_void*)l, 16, 0, 0);
}

#define NH 16
#define DK 64
#define SEQ 2048
#define DIM 1024
#define NEG_INF_F (-1.0e9f)

static __device__ __forceinline__ unsigned short f2bf_bits(float f) {
    bf16 t = __float2bfloat16(f);
    return *reinterpret_cast<unsigned short*>(&t);
}

// ---------------- fused convert f32 -> bf16 for q,k,v ----------------
__global__ void cvt_all_kernel(const float* __restrict__ q, const float* __restrict__ k,
                               const float* __restrict__ v, bf16* __restrict__ qb,
                               bf16* __restrict__ kb, bf16* __restrict__ vb) {
    const int N4 = 2 * SEQ * DIM / 4;
    int i = blockIdx.x * blockDim.x + threadIdx.x;
    int sel = i / N4, j = i - sel * N4;
    const float* in = (sel == 0) ? q : (sel == 1) ? k : v;
    bf16* out = (sel == 0) ? qb : (sel == 1) ? kb : vb;
    float4 x = reinterpret_cast<const float4*>(in)[j];
    ushort4 u;
    u.x = f2bf_bits(x.x);
    u.y = f2bf_bits(x.y);
    u.z = f2bf_bits(x.z);
    u.w = f2bf_bits(x.w);
    reinterpret_cast<ushort4*>(out)[j] = u;
}

// ---------------- fused W (K x N) f32 -> Wt (N x K) bf16 for 4 weights ----------------
__global__ void transpose_cvt_kernel(const float* __restrict__ Wq, const float* __restrict__ Wk,
                                     const float* __restrict__ Wv, const float* __restrict__ Wo,
                                     bf16* __restrict__ Wqt, bf16* __restrict__ Wkt,
                                     bf16* __restrict__ Wvt, bf16* __restrict__ Wot) {
    __shared__ float t[32][33];
    const int z = blockIdx.z;
    const float* W = (z == 0) ? Wq : (z == 1) ? Wk : (z == 2) ? Wv : Wo;
    bf16* Wt = (z == 0) ? Wqt : (z == 1) ? Wkt : (z == 2) ? Wvt : Wot;
    int n0 = blockIdx.x * 32, k0 = blockIdx.y * 32;
    int tx = threadIdx.x, ty = threadIdx.y;
#pragma unroll
    for (int i = 0; i < 4; i++)
        t[ty + i * 8][tx] = W[(size_t)(k0 + ty + i * 8) * DIM + n0 + tx];
    __syncthreads();
#pragma unroll
    for (int i = 0; i < 4; i++)
        Wt[(size_t)(n0 + ty + i * 8) * DIM + k0 + tx] = __float2bfloat16(t[tx][ty + i * 8]);
}

// ---------------- fused QKV projection GEMM (unchanged, verified r8/r10/r13) ----------------
__global__ __launch_bounds__(256) void qkv_gemm_kernel(
    const bf16* __restrict__ qb, const bf16* __restrict__ kb, const bf16* __restrict__ vb,
    const bf16* __restrict__ Wcat,
    const float* __restrict__ bq, const float* __restrict__ bk, const float* __restrict__ bv,
    bf16* __restrict__ Qh, bf16* __restrict__ Kh, bf16* __restrict__ Vt)
{
    __shared__ __align__(16) bf16 Xs[2][128 * 32];
    __shared__ __align__(16) bf16 Ws[2][128 * 32];
    const int tid = threadIdx.x;
    const int w = tid >> 6, l = tid & 63;
    const int l15 = l & 15, l4 = l >> 4;
    const int lin = blockIdx.x;                 // 768 = 8 XCD x 96
    const int swz = (lin & 7) * 96 + (lin >> 3);
    const int proj = swz >> 8;
    const int rem = swz & 255;
    const int m0 = (rem >> 3) * 128;
    const int n0 = (rem & 7) * 128;
    const bf16* X = (proj == 0) ? qb : (proj == 1) ? kb : vb;
    const bf16* Wt = Wcat + (size_t)proj * DIM * DIM + (size_t)n0 * DIM;
    const float* bias = (proj == 0) ? bq : (proj == 1) ? bk : bv;
    const int wr = w >> 1, wc = w & 1;
    f32x4 acc[4][4] = {};

    const int c0 = tid, c1 = 256 + tid;
    const int r0 = c0 >> 2, ch0 = c0 & 3;
    const int r1 = c1 >> 2, ch1 = c1 & 3;
    const bf16* Xp = X + (size_t)m0 * DIM;

    gload_lds16(&Xp[(size_t)r0 * DIM + ch0 * 8], &Xs[0][c0 * 8]);
    gload_lds16(&Xp[(size_t)r1 * DIM + ch1 * 8], &Xs[0][c1 * 8]);
    gload_lds16(&Wt[(size_t)r0 * DIM + ch0 * 8], &Ws[0][c0 * 8]);
    gload_lds16(&Wt[(size_t)r1 * DIM + ch1 * 8], &Ws[0][c1 * 8]);
    __syncthreads();

    int cur = 0;
    for (int k0 = 0; k0 < DIM; k0 += 32) {
        if (k0 + 32 < DIM) {
            gload_lds16(&Xp[(size_t)r0 * DIM + k0 + 32 + ch0 * 8], &Xs[cur ^ 1][c0 * 8]);
            gload_lds16(&Xp[(size_t)r1 * DIM + k0 + 32 + ch1 * 8], &Xs[cur ^ 1][c1 * 8]);
            gload_lds16(&Wt[(size_t)r0 * DIM + k0 + 32 + ch0 * 8], &Ws[cur ^ 1][c0 * 8]);
            gload_lds16(&Wt[(size_t)r1 * DIM + k0 + 32 + ch1 * 8], &Ws[cur ^ 1][c1 * 8]);
        }
        short8 af[4], bfr[4];
#pragma unroll
        for (int mi = 0; mi < 4; mi++)
            af[mi] = *reinterpret_cast<const short8*>(&Xs[cur][(wr * 64 + mi * 16 + l15) * 32 + l4 * 8]);
#pragma unroll
        for (int ni = 0; ni < 4; ni++)
            bfr[ni] = *reinterpret_cast<const short8*>(&Ws[cur][(wc * 64 + ni * 16 + l15) * 32 + l4 * 8]);
#pragma unroll
        for (int mi = 0; mi < 4; mi++)
#pragma unroll
            for (int ni = 0; ni < 4; ni++)
                acc[mi][ni] = __builtin_amdgcn_mfma_f32_16x16x32_bf16(af[mi], bfr[ni], acc[mi][ni], 0, 0, 0);
        __syncthreads();
        cur ^= 1;
    }

#pragma unroll
    for (int mi = 0; mi < 4; mi++) {
#pragma unroll
        for (int ni = 0; ni < 4; ni++) {
            int n = n0 + wc * 64 + ni * 16 + l15;
            float bv = bias[n];
            int h = n >> 6, d = n & 63;
#pragma unroll
            for (int j = 0; j < 4; j++) {
                int m = m0 + wr * 64 + mi * 16 + l4 * 4 + j;
                float val = acc[mi][ni][j] + bv;
                int b = m >> 11, s = m & 2047;
                if (proj == 0)
                    Qh[((size_t)(b * NH + h) * SEQ + s) * DK + d] = __float2bfloat16(val * 0.125f);
                else if (proj == 1)
                    Kh[((size_t)(b * NH + h) * SEQ + s) * DK + d] = __float2bfloat16(val);
                else
                    Vt[((size_t)(b * NH + h) * DK + d) * SEQ + s] = __float2bfloat16(val);
            }
        }
    }
}

// ---------------- O projection GEMM (unchanged, verified r8/r10/r13) ----------------
__global__ __launch_bounds__(256) void o_gemm_kernel(
    const bf16* __restrict__ X, const bf16* __restrict__ Wt,
    const float* __restrict__ bias, float* __restrict__ out)
{
    __shared__ __align__(16) bf16 Xs[2][64 * 32];
    __shared__ __align__(16) bf16 Ws[2][128 * 32];
    const int tid = threadIdx.x;
    const int w = tid >> 6, l = tid & 63;
    const int l15 = l & 15, l4 = l >> 4;
    const int lin = blockIdx.x;
    const int swz = (lin & 7) * 64 + (lin >> 3);
    const int m0 = (swz >> 3) * 64;
    const int n0 = (swz & 7) * 128;
    const int wr = w >> 1, wc = w & 1;
    f32x4 acc[2][4] = {};

    const int c0 = tid, c1 = 256 + tid;
    const int r0 = c0 >> 2, ch0 = c0 & 3;
    const int r1 = c1 >> 2, ch1 = c1 & 3;
    const bf16* Xp = X + (size_t)m0 * DIM;
    const bf16* Wp = Wt + (size_t)n0 * DIM;

    gload_lds16(&Xp[(size_t)r0 * DIM + ch0 * 8], &Xs[0][c0 * 8]);
    gload_lds16(&Wp[(size_t)r0 * DIM + ch0 * 8], &Ws[0][c0 * 8]);
    gload_lds16(&Wp[(size_t)r1 * DIM + ch1 * 8], &Ws[0][c1 * 8]);
    __syncthreads();

    int cur = 0;
    for (int k0 = 0; k0 < DIM; k0 += 32) {
        if (k0 + 32 < DIM) {
            gload_lds16(&Xp[(size_t)r0 * DIM + k0 + 32 + ch0 * 8], &Xs[cur ^ 1][c0 * 8]);
            gload_lds16(&Wp[(size_t)r0 * DIM + k0 + 32 + ch0 * 8], &Ws[cur ^ 1][c0 * 8]);
            gload_lds16(&Wp[(size_t)r1 * DIM + k0 + 32 + ch1 * 8], &Ws[cur ^ 1][c1 * 8]);
        }
        short8 af[2], bfr[4];
#pragma unroll
        for (int mi = 0; mi < 2; mi++)
            af[mi] = *reinterpret_cast<const short8*>(&Xs[cur][(wr * 32 + mi * 16 + l15) * 32 + l4 * 8]);
#pragma unroll
        for (int ni = 0; ni < 4; ni++)
            bfr[ni] = *reinterpret_cast<const short8*>(&Ws[cur][(wc * 64 + ni * 16 + l15) * 32 + l4 * 8]);
#pragma unroll
        for (int mi = 0; mi < 2; mi++)
#pragma unroll
            for (int ni = 0; ni < 4; ni++)
                acc[mi][ni] = __builtin_amdgcn_mfma_f32_16x16x32_bf16(af[mi], bfr[ni], acc[mi][ni], 0, 0, 0);
        __syncthreads();
        cur ^= 1;
    }

#pragma unroll
    for (int mi = 0; mi < 2; mi++) {
#pragma unroll
        for (int ni = 0; ni < 4; ni++) {
            int n = n0 + wc * 64 + ni * 16 + l15;
            float bv = bias[n];
#pragma unroll
            for (int j = 0; j < 4; j++) {
                int m = m0 + wr * 32 + mi * 16 + l4 * 4 + j;
                out[(size_t)m * DIM + n] = acc[mi][ni][j] + bv;
            }
        }
    }
}

// ---------------- fused flash attention: KVBLK=128, paired-tile 1KB score bursts ----------------
// r13 structure. Even tiles stash masked scores in registers (sprev); odd tiles write
// both tiles' scores back-to-back -> 1KB contiguous per q-row per burst.
__global__ __launch_bounds__(512) void attn_kernel(
    const bf16* __restrict__ Qh, const bf16* __restrict__ Kh,
    const bf16* __restrict__ Vt, const int* __restrict__ mask,
    float* __restrict__ scores, bf16* __restrict__ attn_c)
{
    __shared__ __align__(16) bf16 Ks[2][128 * 68];   // K [kv 128][dk 64], stride 68
    __shared__ __align__(16) bf16 Vs[2][64 * 132];   // V^T [dk 64][kv 128], stride 132
    __shared__ __align__(16) bf16 Ps[128 * 132];     // P [q 128][kv 128], stride 132
    const int tid = threadIdx.x;
    const int w = tid >> 6, l = tid & 63;
    const int l15 = l & 15, l4 = l >> 4;
    const int lin = blockIdx.x;                 // 512 = 8 XCD x 64
    const int swz = (lin & 7) * 64 + (lin >> 3);
    const int bh = swz >> 4;
    const int q0 = (swz & 15) * 128;
    const int b = bh >> 4, h = bh & 15;
    const size_t head = (size_t)bh * SEQ * DK;

    const int ck0 = tid, ck1 = 512 + tid;
    const int kR0 = ck0 >> 3, kS0 = ck0 & 7;
    const int kR1 = ck1 >> 3, kS1 = ck1 & 7;
    const int vR0 = ck0 >> 4, vS0 = ck0 & 15;
    const int vR1 = ck1 >> 4, vS1 = ck1 & 15;

    const int* mrow = mask + b * SEQ;

    short8 aq[2];
#pragma unroll
    for (int ks = 0; ks < 2; ks++)
        aq[ks] = *reinterpret_cast<const short8*>(
            &Qh[head + (size_t)(q0 + w * 16 + l15) * DK + ks * 32 + l4 * 8]);

    {
        short8 k0v = *reinterpret_cast<const short8*>(&Kh[head + (size_t)kR0 * DK + kS0 * 8]);
        short8 k1v = *reinterpret_cast<const short8*>(&Kh[head + (size_t)kR1 * DK + kS1 * 8]);
        short8 v0v = *reinterpret_cast<const short8*>(&Vt[head + (size_t)vR0 * SEQ + vS0 * 8]);
        short8 v1v = *reinterpret_cast<const short8*>(&Vt[head + (size_t)vR1 * SEQ + vS1 * 8]);
        *reinterpret_cast<short8*>(&Ks[0][kR0 * 68 + kS0 * 8]) = k0v;
        *reinterpret_cast<short8*>(&Ks[0][kR1 * 68 + kS1 * 8]) = k1v;
        *reinterpret_cast<short8*>(&Vs[0][vR0 * 132 + vS0 * 8]) = v0v;
        *reinterpret_cast<short8*>(&Vs[0][vR1 * 132 + vS1 * 8]) = v1v;
    }
    __syncthreads();

    f32x4 oacc[4] = {};
    f32x4 sprev[8];                     // masked scores of the previous (even) tile
    float mrun[4], lrun[4];
#pragma unroll
    for (int j = 0; j < 4; j++) { mrun[j] = -INFINITY; lrun[j] = 0.f; }

    int cur = 0;
    for (int t = 0; t < SEQ / 128; t++) {
        const int kv0 = t * 128;
        const bool more = t < (SEQ / 128 - 1);
        short8 nk0, nk1, nv0, nv1;
        if (more) {
            nk0 = *reinterpret_cast<const short8*>(&Kh[head + (size_t)(kv0 + 128 + kR0) * DK + kS0 * 8]);
            nk1 = *reinterpret_cast<const short8*>(&Kh[head + (size_t)(kv0 + 128 + kR1) * DK + kS1 * 8]);
            nv0 = *reinterpret_cast<const short8*>(&Vt[head + (size_t)vR0 * SEQ + kv0 + 128 + vS0 * 8]);
            nv1 = *reinterpret_cast<const short8*>(&Vt[head + (size_t)vR1 * SEQ + kv0 + 128 + vS1 * 8]);
        }

        // S = Q K^T
        f32x4 sacc[8] = {};
#pragma unroll
        for (int ks = 0; ks < 2; ks++) {
#pragma unroll
            for (int ni = 0; ni < 8; ni++) {
                short8 bk = *reinterpret_cast<const short8*>(
                    &Ks[cur][(ni * 16 + l15) * 68 + ks * 32 + l4 * 8]);
                sacc[ni] = __builtin_amdgcn_mfma_f32_16x16x32_bf16(aq[ks], bk, sacc[ni], 0, 0, 0);
            }
        }

        // mask (L1-hot)
#pragma unroll
        for (int ni = 0; ni < 8; ni++) {
            int mk = mrow[kv0 + ni * 16 + l15];
            if (mk == 0) {
#pragma unroll
                for (int j = 0; j < 4; j++) sacc[ni][j] = NEG_INF_F;
            }
        }

        // scores: even tile -> stash; odd tile -> write BOTH tiles (1KB/row contiguous)
        if ((t & 1) == 0) {
#pragma unroll
            for (int ni = 0; ni < 8; ni++) sprev[ni] = sacc[ni];
        } else {
            size_t base = ((size_t)bh * SEQ + q0 + w * 16) * SEQ + (kv0 - 128);
#pragma unroll
            for (int j = 0; j < 4; j++) {
                size_t rb = base + (size_t)(l4 * 4 + j) * SEQ;
#pragma unroll
                for (int ni = 0; ni < 8; ni++)
                    __builtin_nontemporal_store(sprev[ni][j], &scores[rb + ni * 16 + l15]);
#pragma unroll
                for (int ni = 0; ni < 8; ni++)
                    __builtin_nontemporal_store(sacc[ni][j], &scores[rb + 128 + ni * 16 + l15]);
            }
        }

        // online softmax; rescale only when row max grows; sum deferred
#pragma unroll
        for (int j = 0; j < 4; j++) {
            float mx = fmaxf(fmaxf(fmaxf(sacc[0][j], sacc[1][j]), fmaxf(sacc[2][j], sacc[3][j])),
                             fmaxf(fmaxf(sacc[4][j], sacc[5][j]), fmaxf(sacc[6][j], sacc[7][j])));
#pragma unroll
            for (int d = 1; d < 16; d <<= 1) mx = fmaxf(mx, __shfl_xor(mx, d));
            if (mx > mrun[j]) {
                float fac = __expf(mrun[j] - mx);
                lrun[j] *= fac;
#pragma unroll
                for (int ni = 0; ni < 4; ni++) oacc[ni][j] *= fac;
                mrun[j] = mx;
            }
            float mcur = mrun[j];
            float ps = 0.f;
#pragma unroll
            for (int ni = 0; ni < 8; ni++) {
                float p = __expf(sacc[ni][j] - mcur);
                sacc[ni][j] = p;
                ps += p;
            }
            lrun[j] += ps;
        }

        // P -> LDS (wave-local rows)
#pragma unroll
        for (int j = 0; j < 4; j++) {
            int r = w * 16 + l4 * 4 + j;
#pragma unroll
            for (int ni = 0; ni < 8; ni++)
                Ps[r * 132 + ni * 16 + l15] = __float2bfloat16(sacc[ni][j]);
        }

        // O += P V
#pragma unroll
        for (int ks = 0; ks < 4; ks++) {
            short8 pa = *reinterpret_cast<const short8*>(
                &Ps[(w * 16 + l15) * 132 + ks * 32 + l4 * 8]);
#pragma unroll
            for (int ni = 0; ni < 4; ni++) {
                short8 vbf = *reinterpret_cast<const short8*>(
                    &Vs[cur][(ni * 16 + l15) * 132 + ks * 32 + l4 * 8]);
                oacc[ni] = __builtin_amdgcn_mfma_f32_16x16x32_bf16(pa, vbf, oacc[ni], 0, 0, 0);
            }
        }

        if (more) {
            *reinterpret_cast<short8*>(&Ks[cur ^ 1][kR0 * 68 + kS0 * 8]) = nk0;
            *reinterpret_cast<short8*>(&Ks[cur ^ 1][kR1 * 68 + kS1 * 8]) = nk1;
            *reinterpret_cast<short8*>(&Vs[cur ^ 1][vR0 * 132 + vS0 * 8]) = nv0;
            *reinterpret_cast<short8*>(&Vs[cur ^ 1][vR1 * 132 + vS1 * 8]) = nv1;
        }
        __syncthreads();
        cur ^= 1;
    }

    // epilogue
#pragma unroll
    for (int j = 0; j < 4; j++) {
        float ls = lrun[j];
#pragma unroll
        for (int d = 1; d < 16; d <<= 1) ls += __shfl_xor(ls, d);
        float inv = 1.f / ls;
        int s = q0 + w * 16 + l4 * 4 + j;
#pragma unroll
        for (int ni = 0; ni < 4; ni++)
            attn_c[((size_t)(b * SEQ + s)) * DIM + h * DK + ni * 16 + l15] =
                __float2bfloat16(oacc[ni][j] * inv);
    }
}

extern "C" void kernel_launch(void* const* d_in, const int* in_sizes, int n_in,
                              void* d_out, int out_size, void* d_ws, size_t ws_size,
                              hipStream_t stream)
{
    const float* q  = (const float*)d_in[0];
    const float* k  = (const float*)d_in[1];
    const float* v  = (const float*)d_in[2];
    const int*  msk = (const int*)d_in[3];
    const float* Wq = (const float*)d_in[4];
    const float* bq = (const float*)d_in[5];
    const float* Wk = (const float*)d_in[6];
    const float* bk = (const float*)d_in[7];
    const float* Wv = (const float*)d_in[8];
    const float* bv = (const float*)d_in[9];
    const float* Wo = (const float*)d_in[10];
    const float* bo = (const float*)d_in[11];

    const size_t MB = 1ull << 20;
    char* ws = (char*)d_ws;
    bf16* qb  = (bf16*)(ws + 0 * MB);
    bf16* kb  = (bf16*)(ws + 8 * MB);
    bf16* vb  = (bf16*)(ws + 16 * MB);
    bf16* Wqt = (bf16*)(ws + 24 * MB);
    bf16* Wkt = (bf16*)(ws + 26 * MB);
    bf16* Wvt = (bf16*)(ws + 28 * MB);
    bf16* Wot = (bf16*)(ws + 30 * MB);
    bf16* QhD = (bf16*)(ws + 32 * MB);
    bf16* KhD = (bf16*)(ws + 40 * MB);
    bf16* VtD = (bf16*)(ws + 48 * MB);
    bf16* att = (bf16*)(ws + 56 * MB);

    float* out = (float*)d_out;
    float* scores = out + (size_t)4096 * 1024;

    cvt_all_kernel<<<3 * 4096, 256, 0, stream>>>(q, k, v, qb, kb, vb);
    transpose_cvt_kernel<<<dim3(32, 32, 4), dim3(32, 8), 0, stream>>>(
        Wq, Wk, Wv, Wo, Wqt, Wkt, Wvt, Wot);

    qkv_gemm_kernel<<<768, 256, 0, stream>>>(qb, kb, vb, Wqt, bq, bk, bv, QhD, KhD, VtD);

    attn_kernel<<<512, 512, 0, stream>>>(QhD, KhD, VtD, msk, scores, att);

    o_gemm_kernel<<<512, 256, 0, stream>>>(att, Wot, bo, out);
}

// Round 15
// 236.651 us; speedup vs baseline: 1.0121x; 1.0121x over previous
//
#include <hip/hip_runtime.h>
#include <hip/hip_bf16.h>

typedef __attribute__((ext_vector_type(8))) short short8;
typedef __attribute__((ext_vector_type(4))) float f32x4;
typedef __hip_bfloat16 bf16;

typedef const void __attribute__((address_space(1))) as1_const_void;
typedef void __attribute__((address_space(3))) as3_void;

static __device__ __forceinline__ void gload_lds16(const bf16* g, bf16* l) {
    __builtin_amdgcn_global_load_lds((as1_const_void*)g, (as3_void*)l, 16, 0, 0);
}

#define NH 16
#define DK 64
#define SEQ 2048
#define DIM 1024
#define NEG_INF_F (-1.0e9f)

static __device__ __forceinline__ unsigned short f2bf_bits(float f) {
    bf16 t = __float2bfloat16(f);
    return *reinterpret_cast<unsigned short*>(&t);
}

// ---------------- fused prep: q/k/v f32->bf16 (blocks 0..12287) + W transpose (12288..16383) ----------------
__global__ void prep_kernel(const float* __restrict__ q, const float* __restrict__ k,
                            const float* __restrict__ v, bf16* __restrict__ qb,
                            bf16* __restrict__ kb, bf16* __restrict__ vb,
                            const float* __restrict__ Wq, const float* __restrict__ Wk,
                            const float* __restrict__ Wv, const float* __restrict__ Wo,
                            bf16* __restrict__ Wqt, bf16* __restrict__ Wkt,
                            bf16* __restrict__ Wvt, bf16* __restrict__ Wot) {
    __shared__ float t[32][33];
    const int tid = threadIdx.x;
    if (blockIdx.x < 12288) {
        const int N4 = 2 * SEQ * DIM / 4;
        int i = blockIdx.x * 256 + tid;
        int sel = i / N4, j = i - sel * N4;
        const float* in = (sel == 0) ? q : (sel == 1) ? k : v;
        bf16* out = (sel == 0) ? qb : (sel == 1) ? kb : vb;
        float4 x = reinterpret_cast<const float4*>(in)[j];
        ushort4 u;
        u.x = f2bf_bits(x.x);
        u.y = f2bf_bits(x.y);
        u.z = f2bf_bits(x.z);
        u.w = f2bf_bits(x.w);
        reinterpret_cast<ushort4*>(out)[j] = u;
    } else {
        int bid = blockIdx.x - 12288;            // 4096 = 4 z x 1024 tiles
        int z = bid >> 10, rem = bid & 1023;
        const float* W = (z == 0) ? Wq : (z == 1) ? Wk : (z == 2) ? Wv : Wo;
        bf16* Wt = (z == 0) ? Wqt : (z == 1) ? Wkt : (z == 2) ? Wvt : Wot;
        int n0 = (rem & 31) * 32, k0 = (rem >> 5) * 32;
        int tx = tid & 31, ty = tid >> 5;        // 32 x 8
#pragma unroll
        for (int i = 0; i < 4; i++)
            t[ty + i * 8][tx] = W[(size_t)(k0 + ty + i * 8) * DIM + n0 + tx];
        __syncthreads();
#pragma unroll
        for (int i = 0; i < 4; i++)
            Wt[(size_t)(n0 + ty + i * 8) * DIM + k0 + tx] = __float2bfloat16(t[tx][ty + i * 8]);
    }
}

// ---------------- fused QKV projection GEMM (unchanged, verified r8/r10/r13) ----------------
__global__ __launch_bounds__(256) void qkv_gemm_kernel(
    const bf16* __restrict__ qb, const bf16* __restrict__ kb, const bf16* __restrict__ vb,
    const bf16* __restrict__ Wcat,
    const float* __restrict__ bq, const float* __restrict__ bk, const float* __restrict__ bv,
    bf16* __restrict__ Qh, bf16* __restrict__ Kh, bf16* __restrict__ Vt)
{
    __shared__ __align__(16) bf16 Xs[2][128 * 32];
    __shared__ __align__(16) bf16 Ws[2][128 * 32];
    const int tid = threadIdx.x;
    const int w = tid >> 6, l = tid & 63;
    const int l15 = l & 15, l4 = l >> 4;
    const int lin = blockIdx.x;                 // 768 = 8 XCD x 96
    const int swz = (lin & 7) * 96 + (lin >> 3);
    const int proj = swz >> 8;
    const int rem = swz & 255;
    const int m0 = (rem >> 3) * 128;
    const int n0 = (rem & 7) * 128;
    const bf16* X = (proj == 0) ? qb : (proj == 1) ? kb : vb;
    const bf16* Wt = Wcat + (size_t)proj * DIM * DIM + (size_t)n0 * DIM;
    const float* bias = (proj == 0) ? bq : (proj == 1) ? bk : bv;
    const int wr = w >> 1, wc = w & 1;
    f32x4 acc[4][4] = {};

    const int c0 = tid, c1 = 256 + tid;
    const int r0 = c0 >> 2, ch0 = c0 & 3;
    const int r1 = c1 >> 2, ch1 = c1 & 3;
    const bf16* Xp = X + (size_t)m0 * DIM;

    gload_lds16(&Xp[(size_t)r0 * DIM + ch0 * 8], &Xs[0][c0 * 8]);
    gload_lds16(&Xp[(size_t)r1 * DIM + ch1 * 8], &Xs[0][c1 * 8]);
    gload_lds16(&Wt[(size_t)r0 * DIM + ch0 * 8], &Ws[0][c0 * 8]);
    gload_lds16(&Wt[(size_t)r1 * DIM + ch1 * 8], &Ws[0][c1 * 8]);
    __syncthreads();

    int cur = 0;
    for (int k0 = 0; k0 < DIM; k0 += 32) {
        if (k0 + 32 < DIM) {
            gload_lds16(&Xp[(size_t)r0 * DIM + k0 + 32 + ch0 * 8], &Xs[cur ^ 1][c0 * 8]);
            gload_lds16(&Xp[(size_t)r1 * DIM + k0 + 32 + ch1 * 8], &Xs[cur ^ 1][c1 * 8]);
            gload_lds16(&Wt[(size_t)r0 * DIM + k0 + 32 + ch0 * 8], &Ws[cur ^ 1][c0 * 8]);
            gload_lds16(&Wt[(size_t)r1 * DIM + k0 + 32 + ch1 * 8], &Ws[cur ^ 1][c1 * 8]);
        }
        short8 af[4], bfr[4];
#pragma unroll
        for (int mi = 0; mi < 4; mi++)
            af[mi] = *reinterpret_cast<const short8*>(&Xs[cur][(wr * 64 + mi * 16 + l15) * 32 + l4 * 8]);
#pragma unroll
        for (int ni = 0; ni < 4; ni++)
            bfr[ni] = *reinterpret_cast<const short8*>(&Ws[cur][(wc * 64 + ni * 16 + l15) * 32 + l4 * 8]);
#pragma unroll
        for (int mi = 0; mi < 4; mi++)
#pragma unroll
            for (int ni = 0; ni < 4; ni++)
                acc[mi][ni] = __builtin_amdgcn_mfma_f32_16x16x32_bf16(af[mi], bfr[ni], acc[mi][ni], 0, 0, 0);
        __syncthreads();
        cur ^= 1;
    }

#pragma unroll
    for (int mi = 0; mi < 4; mi++) {
#pragma unroll
        for (int ni = 0; ni < 4; ni++) {
            int n = n0 + wc * 64 + ni * 16 + l15;
            float bv = bias[n];
            int h = n >> 6, d = n & 63;
#pragma unroll
            for (int j = 0; j < 4; j++) {
                int m = m0 + wr * 64 + mi * 16 + l4 * 4 + j;
                float val = acc[mi][ni][j] + bv;
                int b = m >> 11, s = m & 2047;
                if (proj == 0)
                    Qh[((size_t)(b * NH + h) * SEQ + s) * DK + d] = __float2bfloat16(val * 0.125f);
                else if (proj == 1)
                    Kh[((size_t)(b * NH + h) * SEQ + s) * DK + d] = __float2bfloat16(val);
                else
                    Vt[((size_t)(b * NH + h) * DK + d) * SEQ + s] = __float2bfloat16(val);
            }
        }
    }
}

// ---------------- O projection GEMM (unchanged, verified r8/r10/r13) ----------------
__global__ __launch_bounds__(256) void o_gemm_kernel(
    const bf16* __restrict__ X, const bf16* __restrict__ Wt,
    const float* __restrict__ bias, float* __restrict__ out)
{
    __shared__ __align__(16) bf16 Xs[2][64 * 32];
    __shared__ __align__(16) bf16 Ws[2][128 * 32];
    const int tid = threadIdx.x;
    const int w = tid >> 6, l = tid & 63;
    const int l15 = l & 15, l4 = l >> 4;
    const int lin = blockIdx.x;
    const int swz = (lin & 7) * 64 + (lin >> 3);
    const int m0 = (swz >> 3) * 64;
    const int n0 = (swz & 7) * 128;
    const int wr = w >> 1, wc = w & 1;
    f32x4 acc[2][4] = {};

    const int c0 = tid, c1 = 256 + tid;
    const int r0 = c0 >> 2, ch0 = c0 & 3;
    const int r1 = c1 >> 2, ch1 = c1 & 3;
    const bf16* Xp = X + (size_t)m0 * DIM;
    const bf16* Wp = Wt + (size_t)n0 * DIM;

    gload_lds16(&Xp[(size_t)r0 * DIM + ch0 * 8], &Xs[0][c0 * 8]);
    gload_lds16(&Wp[(size_t)r0 * DIM + ch0 * 8], &Ws[0][c0 * 8]);
    gload_lds16(&Wp[(size_t)r1 * DIM + ch1 * 8], &Ws[0][c1 * 8]);
    __syncthreads();

    int cur = 0;
    for (int k0 = 0; k0 < DIM; k0 += 32) {
        if (k0 + 32 < DIM) {
            gload_lds16(&Xp[(size_t)r0 * DIM + k0 + 32 + ch0 * 8], &Xs[cur ^ 1][c0 * 8]);
            gload_lds16(&Wp[(size_t)r0 * DIM + k0 + 32 + ch0 * 8], &Ws[cur ^ 1][c0 * 8]);
            gload_lds16(&Wp[(size_t)r1 * DIM + k0 + 32 + ch1 * 8], &Ws[cur ^ 1][c1 * 8]);
        }
        short8 af[2], bfr[4];
#pragma unroll
        for (int mi = 0; mi < 2; mi++)
            af[mi] = *reinterpret_cast<const short8*>(&Xs[cur][(wr * 32 + mi * 16 + l15) * 32 + l4 * 8]);
#pragma unroll
        for (int ni = 0; ni < 4; ni++)
            bfr[ni] = *reinterpret_cast<const short8*>(&Ws[cur][(wc * 64 + ni * 16 + l15) * 32 + l4 * 8]);
#pragma unroll
        for (int mi = 0; mi < 2; mi++)
#pragma unroll
            for (int ni = 0; ni < 4; ni++)
                acc[mi][ni] = __builtin_amdgcn_mfma_f32_16x16x32_bf16(af[mi], bfr[ni], acc[mi][ni], 0, 0, 0);
        __syncthreads();
        cur ^= 1;
    }

#pragma unroll
    for (int mi = 0; mi < 2; mi++) {
#pragma unroll
        for (int ni = 0; ni < 4; ni++) {
            int n = n0 + wc * 64 + ni * 16 + l15;
            float bv = bias[n];
#pragma unroll
            for (int j = 0; j < 4; j++) {
                int m = m0 + wr * 32 + mi * 16 + l4 * 4 + j;
                out[(size_t)m * DIM + n] = acc[mi][ni][j] + bv;
            }
        }
    }
}

// ---------------- fused flash attention: QBLK=256, KVBLK=128 ----------------
// 512 threads = 8 waves x 32 q-rows (2 mi-halves of 16). Grid 256 = exactly 1 block/CU,
// single round (r13 ran 2 rounds of 512 blocks). Same 512B score bursts, same
// one-barrier reg-staged dbuf K/V as r13.
__global__ __launch_bounds__(512) void attn_kernel(
    const bf16* __restrict__ Qh, const bf16* __restrict__ Kh,
    const bf16* __restrict__ Vt, const int* __restrict__ mask,
    float* __restrict__ scores, bf16* __restrict__ attn_c)
{
    __shared__ __align__(16) bf16 Ks[2][128 * 68];   // K [kv 128][dk 64]
    __shared__ __align__(16) bf16 Vs[2][64 * 132];   // V^T [dk 64][kv 128]
    __shared__ __align__(16) bf16 Ps[256 * 132];     // P [q 256][kv 128]
    const int tid = threadIdx.x;
    const int w = tid >> 6, l = tid & 63;
    const int l15 = l & 15, l4 = l >> 4;
    const int lin = blockIdx.x;                 // 256 = 8 XCD x 32
    const int swz = (lin & 7) * 32 + (lin >> 3);
    const int bh = swz >> 3;                    // 32 heads
    const int q0 = (swz & 7) * 256;             // 8 q-tiles of 256
    const int b = bh >> 4, h = bh & 15;
    const size_t head = (size_t)bh * SEQ * DK;

    const int ck0 = tid, ck1 = 512 + tid;
    const int kR0 = ck0 >> 3, kS0 = ck0 & 7;
    const int kR1 = ck1 >> 3, kS1 = ck1 & 7;
    const int vR0 = ck0 >> 4, vS0 = ck0 & 15;
    const int vR1 = ck1 >> 4, vS1 = ck1 & 15;

    const int* mrow = mask + b * SEQ;

    // Q fragments (pre-scaled 1/8): q = q0 + w*32 + mi*16 + l15
    short8 aq[2][2];
#pragma unroll
    for (int mi = 0; mi < 2; mi++)
#pragma unroll
        for (int ks = 0; ks < 2; ks++)
            aq[mi][ks] = *reinterpret_cast<const short8*>(
                &Qh[head + (size_t)(q0 + w * 32 + mi * 16 + l15) * DK + ks * 32 + l4 * 8]);

    {
        short8 k0v = *reinterpret_cast<const short8*>(&Kh[head + (size_t)kR0 * DK + kS0 * 8]);
        short8 k1v = *reinterpret_cast<const short8*>(&Kh[head + (size_t)kR1 * DK + kS1 * 8]);
        short8 v0v = *reinterpret_cast<const short8*>(&Vt[head + (size_t)vR0 * SEQ + vS0 * 8]);
        short8 v1v = *reinterpret_cast<const short8*>(&Vt[head + (size_t)vR1 * SEQ + vS1 * 8]);
        *reinterpret_cast<short8*>(&Ks[0][kR0 * 68 + kS0 * 8]) = k0v;
        *reinterpret_cast<short8*>(&Ks[0][kR1 * 68 + kS1 * 8]) = k1v;
        *reinterpret_cast<short8*>(&Vs[0][vR0 * 132 + vS0 * 8]) = v0v;
        *reinterpret_cast<short8*>(&Vs[0][vR1 * 132 + vS1 * 8]) = v1v;
    }
    __syncthreads();

    f32x4 oacc[2][4] = {};
    float mrun[2][4], lrun[2][4];
#pragma unroll
    for (int mi = 0; mi < 2; mi++)
#pragma unroll
        for (int j = 0; j < 4; j++) { mrun[mi][j] = -INFINITY; lrun[mi][j] = 0.f; }

    int cur = 0;
    for (int t = 0; t < SEQ / 128; t++) {
        const int kv0 = t * 128;
        const bool more = t < (SEQ / 128 - 1);
        short8 nk0, nk1, nv0, nv1;
        if (more) {
            nk0 = *reinterpret_cast<const short8*>(&Kh[head + (size_t)(kv0 + 128 + kR0) * DK + kS0 * 8]);
            nk1 = *reinterpret_cast<const short8*>(&Kh[head + (size_t)(kv0 + 128 + kR1) * DK + kS1 * 8]);
            nv0 = *reinterpret_cast<const short8*>(&Vt[head + (size_t)vR0 * SEQ + kv0 + 128 + vS0 * 8]);
            nv1 = *reinterpret_cast<const short8*>(&Vt[head + (size_t)vR1 * SEQ + kv0 + 128 + vS1 * 8]);
        }

        // S = Q K^T for both mi halves
        f32x4 sacc[2][8] = {};
#pragma unroll
        for (int ks = 0; ks < 2; ks++) {
#pragma unroll
            for (int ni = 0; ni < 8; ni++) {
                short8 bk = *reinterpret_cast<const short8*>(
                    &Ks[cur][(ni * 16 + l15) * 68 + ks * 32 + l4 * 8]);
#pragma unroll
                for (int mi = 0; mi < 2; mi++)
                    sacc[mi][ni] = __builtin_amdgcn_mfma_f32_16x16x32_bf16(aq[mi][ks], bk, sacc[mi][ni], 0, 0, 0);
            }
        }

        // mask (L1-hot)
#pragma unroll
        for (int ni = 0; ni < 8; ni++) {
            int mk = mrow[kv0 + ni * 16 + l15];
            if (mk == 0) {
#pragma unroll
                for (int mi = 0; mi < 2; mi++)
#pragma unroll
                    for (int j = 0; j < 4; j++) sacc[mi][ni][j] = NEG_INF_F;
            }
        }

        // masked raw scores -> d_out (512B burst per row per iter)
#pragma unroll
        for (int mi = 0; mi < 2; mi++) {
            size_t base = ((size_t)bh * SEQ + q0 + w * 32 + mi * 16) * SEQ + kv0;
#pragma unroll
            for (int j = 0; j < 4; j++) {
                size_t rb = base + (size_t)(l4 * 4 + j) * SEQ;
#pragma unroll
                for (int ni = 0; ni < 8; ni++)
                    __builtin_nontemporal_store(sacc[mi][ni][j], &scores[rb + ni * 16 + l15]);
            }
        }

        // online softmax per mi per row
#pragma unroll
        for (int mi = 0; mi < 2; mi++)
#pragma unroll
            for (int j = 0; j < 4; j++) {
                float mx = fmaxf(fmaxf(fmaxf(sacc[mi][0][j], sacc[mi][1][j]), fmaxf(sacc[mi][2][j], sacc[mi][3][j])),
                                 fmaxf(fmaxf(sacc[mi][4][j], sacc[mi][5][j]), fmaxf(sacc[mi][6][j], sacc[mi][7][j])));
#pragma unroll
                for (int d = 1; d < 16; d <<= 1) mx = fmaxf(mx, __shfl_xor(mx, d));
                if (mx > mrun[mi][j]) {
                    float fac = __expf(mrun[mi][j] - mx);
                    lrun[mi][j] *= fac;
#pragma unroll
                    for (int ni = 0; ni < 4; ni++) oacc[mi][ni][j] *= fac;
                    mrun[mi][j] = mx;
                }
                float mcur = mrun[mi][j];
                float ps = 0.f;
#pragma unroll
                for (int ni = 0; ni < 8; ni++) {
                    float p = __expf(sacc[mi][ni][j] - mcur);
                    sacc[mi][ni][j] = p;
                    ps += p;
                }
                lrun[mi][j] += ps;
            }

        // P -> LDS (wave-local rows w*32 .. w*32+31)
#pragma unroll
        for (int mi = 0; mi < 2; mi++)
#pragma unroll
            for (int j = 0; j < 4; j++) {
                int r = w * 32 + mi * 16 + l4 * 4 + j;
#pragma unroll
                for (int ni = 0; ni < 8; ni++)
                    Ps[r * 132 + ni * 16 + l15] = __float2bfloat16(sacc[mi][ni][j]);
            }

        // O += P V
#pragma unroll
        for (int ks = 0; ks < 4; ks++) {
            short8 pa[2];
#pragma unroll
            for (int mi = 0; mi < 2; mi++)
                pa[mi] = *reinterpret_cast<const short8*>(
                    &Ps[(w * 32 + mi * 16 + l15) * 132 + ks * 32 + l4 * 8]);
#pragma unroll
            for (int ni = 0; ni < 4; ni++) {
                short8 vbf = *reinterpret_cast<const short8*>(
                    &Vs[cur][(ni * 16 + l15) * 132 + ks * 32 + l4 * 8]);
#pragma unroll
                for (int mi = 0; mi < 2; mi++)
                    oacc[mi][ni] = __builtin_amdgcn_mfma_f32_16x16x32_bf16(pa[mi], vbf, oacc[mi][ni], 0, 0, 0);
            }
        }

        if (more) {
            *reinterpret_cast<short8*>(&Ks[cur ^ 1][kR0 * 68 + kS0 * 8]) = nk0;
            *reinterpret_cast<short8*>(&Ks[cur ^ 1][kR1 * 68 + kS1 * 8]) = nk1;
            *reinterpret_cast<short8*>(&Vs[cur ^ 1][vR0 * 132 + vS0 * 8]) = nv0;
            *reinterpret_cast<short8*>(&Vs[cur ^ 1][vR1 * 132 + vS1 * 8]) = nv1;
        }
        __syncthreads();
        cur ^= 1;
    }

    // epilogue
#pragma unroll
    for (int mi = 0; mi < 2; mi++)
#pragma unroll
        for (int j = 0; j < 4; j++) {
            float ls = lrun[mi][j];
#pragma unroll
            for (int d = 1; d < 16; d <<= 1) ls += __shfl_xor(ls, d);
            float inv = 1.f / ls;
            int s = q0 + w * 32 + mi * 16 + l4 * 4 + j;
#pragma unroll
            for (int ni = 0; ni < 4; ni++)
                attn_c[((size_t)(b * SEQ + s)) * DIM + h * DK + ni * 16 + l15] =
                    __float2bfloat16(oacc[mi][ni][j] * inv);
        }
}

extern "C" void kernel_launch(void* const* d_in, const int* in_sizes, int n_in,
                              void* d_out, int out_size, void* d_ws, size_t ws_size,
                              hipStream_t stream)
{
    const float* q  = (const float*)d_in[0];
    const float* k  = (const float*)d_in[1];
    const float* v  = (const float*)d_in[2];
    const int*  msk = (const int*)d_in[3];
    const float* Wq = (const float*)d_in[4];
    const float* bq = (const float*)d_in[5];
    const float* Wk = (const float*)d_in[6];
    const float* bk = (const float*)d_in[7];
    const float* Wv = (const float*)d_in[8];
    const float* bv = (const float*)d_in[9];
    const float* Wo = (const float*)d_in[10];
    const float* bo = (const float*)d_in[11];

    const size_t MB = 1ull << 20;
    char* ws = (char*)d_ws;
    bf16* qb  = (bf16*)(ws + 0 * MB);
    bf16* kb  = (bf16*)(ws + 8 * MB);
    bf16* vb  = (bf16*)(ws + 16 * MB);
    bf16* Wqt = (bf16*)(ws + 24 * MB);
    bf16* Wkt = (bf16*)(ws + 26 * MB);
    bf16* Wvt = (bf16*)(ws + 28 * MB);
    bf16* Wot = (bf16*)(ws + 30 * MB);
    bf16* QhD = (bf16*)(ws + 32 * MB);
    bf16* KhD = (bf16*)(ws + 40 * MB);
    bf16* VtD = (bf16*)(ws + 48 * MB);
    bf16* att = (bf16*)(ws + 56 * MB);

    float* out = (float*)d_out;
    float* scores = out + (size_t)4096 * 1024;

    prep_kernel<<<16384, 256, 0, stream>>>(q, k, v, qb, kb, vb,
                                           Wq, Wk, Wv, Wo, Wqt, Wkt, Wvt, Wot);

    qkv_gemm_kernel<<<768, 256, 0, stream>>>(qb, kb, vb, Wqt, bq, bk, bv, QhD, KhD, VtD);

    attn_kernel<<<256, 512, 0, stream>>>(QhD, KhD, VtD, msk, scores, att);

    o_gemm_kernel<<<512, 256, 0, stream>>>(att, Wot, bo, out);
}

// Round 16
// 219.222 us; speedup vs baseline: 1.0925x; 1.0795x over previous
//
#include <hip/hip_runtime.h>
#include <hip/hip_bf16.h>

typedef __attribute__((ext_vector_type(8))) short short8;
typedef __attribute__((ext_vector_type(4))) float f32x4;
typedef __hip_bfloat16 bf16;

typedef const void __attribute__((address_space(1))) as1_const_void;
typedef void __attribute__((address_space(3))) as3_void;

static __device__ __forceinline__ void gload_lds16(const bf16* g, bf16* l) {
    __builtin_amdgcn_global_load_lds((as1_const_void*)g, (as3_void*)l, 16, 0, 0);
}

#define NH 16
#define DK 64
#define SEQ 2048
#define DIM 1024
#define NEG_INF_F (-1.0e9f)

static __device__ __forceinline__ unsigned short f2bf_bits(float f) {
    bf16 t = __float2bfloat16(f);
    return *reinterpret_cast<unsigned short*>(&t);
}

// ---------------- fused prep: q/k/v f32->bf16 (blocks 0..12287) + W transpose (12288..16383) ----------------
__global__ void prep_kernel(const float* __restrict__ q, const float* __restrict__ k,
                            const float* __restrict__ v, bf16* __restrict__ qb,
                            bf16* __restrict__ kb, bf16* __restrict__ vb,
                            const float* __restrict__ Wq, const float* __restrict__ Wk,
                            const float* __restrict__ Wv, const float* __restrict__ Wo,
                            bf16* __restrict__ Wqt, bf16* __restrict__ Wkt,
                            bf16* __restrict__ Wvt, bf16* __restrict__ Wot) {
    __shared__ float t[32][33];
    const int tid = threadIdx.x;
    if (blockIdx.x < 12288) {
        const int N4 = 2 * SEQ * DIM / 4;
        int i = blockIdx.x * 256 + tid;
        int sel = i / N4, j = i - sel * N4;
        const float* in = (sel == 0) ? q : (sel == 1) ? k : v;
        bf16* out = (sel == 0) ? qb : (sel == 1) ? kb : vb;
        float4 x = reinterpret_cast<const float4*>(in)[j];
        ushort4 u;
        u.x = f2bf_bits(x.x);
        u.y = f2bf_bits(x.y);
        u.z = f2bf_bits(x.z);
        u.w = f2bf_bits(x.w);
        reinterpret_cast<ushort4*>(out)[j] = u;
    } else {
        int bid = blockIdx.x - 12288;            // 4096 = 4 z x 1024 tiles
        int z = bid >> 10, rem = bid & 1023;
        const float* W = (z == 0) ? Wq : (z == 1) ? Wk : (z == 2) ? Wv : Wo;
        bf16* Wt = (z == 0) ? Wqt : (z == 1) ? Wkt : (z == 2) ? Wvt : Wot;
        int n0 = (rem & 31) * 32, k0 = (rem >> 5) * 32;
        int tx = tid & 31, ty = tid >> 5;        // 32 x 8
#pragma unroll
        for (int i = 0; i < 4; i++)
            t[ty + i * 8][tx] = W[(size_t)(k0 + ty + i * 8) * DIM + n0 + tx];
        __syncthreads();
#pragma unroll
        for (int i = 0; i < 4; i++)
            Wt[(size_t)(n0 + ty + i * 8) * DIM + k0 + tx] = __float2bfloat16(t[tx][ty + i * 8]);
    }
}

// ---------------- fused QKV projection GEMM (unchanged, verified r8/r10/r13) ----------------
__global__ __launch_bounds__(256) void qkv_gemm_kernel(
    const bf16* __restrict__ qb, const bf16* __restrict__ kb, const bf16* __restrict__ vb,
    const bf16* __restrict__ Wcat,
    const float* __restrict__ bq, const float* __restrict__ bk, const float* __restrict__ bv,
    bf16* __restrict__ Qh, bf16* __restrict__ Kh, bf16* __restrict__ Vt)
{
    __shared__ __align__(16) bf16 Xs[2][128 * 32];
    __shared__ __align__(16) bf16 Ws[2][128 * 32];
    const int tid = threadIdx.x;
    const int w = tid >> 6, l = tid & 63;
    const int l15 = l & 15, l4 = l >> 4;
    const int lin = blockIdx.x;                 // 768 = 8 XCD x 96
    const int swz = (lin & 7) * 96 + (lin >> 3);
    const int proj = swz >> 8;
    const int rem = swz & 255;
    const int m0 = (rem >> 3) * 128;
    const int n0 = (rem & 7) * 128;
    const bf16* X = (proj == 0) ? qb : (proj == 1) ? kb : vb;
    const bf16* Wt = Wcat + (size_t)proj * DIM * DIM + (size_t)n0 * DIM;
    const float* bias = (proj == 0) ? bq : (proj == 1) ? bk : bv;
    const int wr = w >> 1, wc = w & 1;
    f32x4 acc[4][4] = {};

    const int c0 = tid, c1 = 256 + tid;
    const int r0 = c0 >> 2, ch0 = c0 & 3;
    const int r1 = c1 >> 2, ch1 = c1 & 3;
    const bf16* Xp = X + (size_t)m0 * DIM;

    gload_lds16(&Xp[(size_t)r0 * DIM + ch0 * 8], &Xs[0][c0 * 8]);
    gload_lds16(&Xp[(size_t)r1 * DIM + ch1 * 8], &Xs[0][c1 * 8]);
    gload_lds16(&Wt[(size_t)r0 * DIM + ch0 * 8], &Ws[0][c0 * 8]);
    gload_lds16(&Wt[(size_t)r1 * DIM + ch1 * 8], &Ws[0][c1 * 8]);
    __syncthreads();

    int cur = 0;
    for (int k0 = 0; k0 < DIM; k0 += 32) {
        if (k0 + 32 < DIM) {
            gload_lds16(&Xp[(size_t)r0 * DIM + k0 + 32 + ch0 * 8], &Xs[cur ^ 1][c0 * 8]);
            gload_lds16(&Xp[(size_t)r1 * DIM + k0 + 32 + ch1 * 8], &Xs[cur ^ 1][c1 * 8]);
            gload_lds16(&Wt[(size_t)r0 * DIM + k0 + 32 + ch0 * 8], &Ws[cur ^ 1][c0 * 8]);
            gload_lds16(&Wt[(size_t)r1 * DIM + k0 + 32 + ch1 * 8], &Ws[cur ^ 1][c1 * 8]);
        }
        short8 af[4], bfr[4];
#pragma unroll
        for (int mi = 0; mi < 4; mi++)
            af[mi] = *reinterpret_cast<const short8*>(&Xs[cur][(wr * 64 + mi * 16 + l15) * 32 + l4 * 8]);
#pragma unroll
        for (int ni = 0; ni < 4; ni++)
            bfr[ni] = *reinterpret_cast<const short8*>(&Ws[cur][(wc * 64 + ni * 16 + l15) * 32 + l4 * 8]);
#pragma unroll
        for (int mi = 0; mi < 4; mi++)
#pragma unroll
            for (int ni = 0; ni < 4; ni++)
                acc[mi][ni] = __builtin_amdgcn_mfma_f32_16x16x32_bf16(af[mi], bfr[ni], acc[mi][ni], 0, 0, 0);
        __syncthreads();
        cur ^= 1;
    }

#pragma unroll
    for (int mi = 0; mi < 4; mi++) {
#pragma unroll
        for (int ni = 0; ni < 4; ni++) {
            int n = n0 + wc * 64 + ni * 16 + l15;
            float bv = bias[n];
            int h = n >> 6, d = n & 63;
#pragma unroll
            for (int j = 0; j < 4; j++) {
                int m = m0 + wr * 64 + mi * 16 + l4 * 4 + j;
                float val = acc[mi][ni][j] + bv;
                int b = m >> 11, s = m & 2047;
                if (proj == 0)
                    Qh[((size_t)(b * NH + h) * SEQ + s) * DK + d] = __float2bfloat16(val * 0.125f);
                else if (proj == 1)
                    Kh[((size_t)(b * NH + h) * SEQ + s) * DK + d] = __float2bfloat16(val);
                else
                    Vt[((size_t)(b * NH + h) * DK + d) * SEQ + s] = __float2bfloat16(val);
            }
        }
    }
}

// ---------------- O projection GEMM (unchanged, verified r8/r10/r13) ----------------
__global__ __launch_bounds__(256) void o_gemm_kernel(
    const bf16* __restrict__ X, const bf16* __restrict__ Wt,
    const float* __restrict__ bias, float* __restrict__ out)
{
    __shared__ __align__(16) bf16 Xs[2][64 * 32];
    __shared__ __align__(16) bf16 Ws[2][128 * 32];
    const int tid = threadIdx.x;
    const int w = tid >> 6, l = tid & 63;
    const int l15 = l & 15, l4 = l >> 4;
    const int lin = blockIdx.x;
    const int swz = (lin & 7) * 64 + (lin >> 3);
    const int m0 = (swz >> 3) * 64;
    const int n0 = (swz & 7) * 128;
    const int wr = w >> 1, wc = w & 1;
    f32x4 acc[2][4] = {};

    const int c0 = tid, c1 = 256 + tid;
    const int r0 = c0 >> 2, ch0 = c0 & 3;
    const int r1 = c1 >> 2, ch1 = c1 & 3;
    const bf16* Xp = X + (size_t)m0 * DIM;
    const bf16* Wp = Wt + (size_t)n0 * DIM;

    gload_lds16(&Xp[(size_t)r0 * DIM + ch0 * 8], &Xs[0][c0 * 8]);
    gload_lds16(&Wp[(size_t)r0 * DIM + ch0 * 8], &Ws[0][c0 * 8]);
    gload_lds16(&Wp[(size_t)r1 * DIM + ch1 * 8], &Ws[0][c1 * 8]);
    __syncthreads();

    int cur = 0;
    for (int k0 = 0; k0 < DIM; k0 += 32) {
        if (k0 + 32 < DIM) {
            gload_lds16(&Xp[(size_t)r0 * DIM + k0 + 32 + ch0 * 8], &Xs[cur ^ 1][c0 * 8]);
            gload_lds16(&Wp[(size_t)r0 * DIM + k0 + 32 + ch0 * 8], &Ws[cur ^ 1][c0 * 8]);
            gload_lds16(&Wp[(size_t)r1 * DIM + k0 + 32 + ch1 * 8], &Ws[cur ^ 1][c1 * 8]);
        }
        short8 af[2], bfr[4];
#pragma unroll
        for (int mi = 0; mi < 2; mi++)
            af[mi] = *reinterpret_cast<const short8*>(&Xs[cur][(wr * 32 + mi * 16 + l15) * 32 + l4 * 8]);
#pragma unroll
        for (int ni = 0; ni < 4; ni++)
            bfr[ni] = *reinterpret_cast<const short8*>(&Ws[cur][(wc * 64 + ni * 16 + l15) * 32 + l4 * 8]);
#pragma unroll
        for (int mi = 0; mi < 2; mi++)
#pragma unroll
            for (int ni = 0; ni < 4; ni++)
                acc[mi][ni] = __builtin_amdgcn_mfma_f32_16x16x32_bf16(af[mi], bfr[ni], acc[mi][ni], 0, 0, 0);
        __syncthreads();
        cur ^= 1;
    }

#pragma unroll
    for (int mi = 0; mi < 2; mi++) {
#pragma unroll
        for (int ni = 0; ni < 4; ni++) {
            int n = n0 + wc * 64 + ni * 16 + l15;
            float bv = bias[n];
#pragma unroll
            for (int j = 0; j < 4; j++) {
                int m = m0 + wr * 32 + mi * 16 + l4 * 4 + j;
                out[(size_t)m * DIM + n] = acc[mi][ni][j] + bv;
            }
        }
    }
}

// ---------------- fused flash attention (r13 verbatim: QBLK=128, KVBLK=128) ----------------
// 512 threads = 8 waves x 16 q-rows. 512B score bursts/row/iter. One barrier/iter,
// reg-staged dbuf K/V (issue-early, write-late).
__global__ __launch_bounds__(512) void attn_kernel(
    const bf16* __restrict__ Qh, const bf16* __restrict__ Kh,
    const bf16* __restrict__ Vt, const int* __restrict__ mask,
    float* __restrict__ scores, bf16* __restrict__ attn_c)
{
    __shared__ __align__(16) bf16 Ks[2][128 * 68];   // K [kv 128][dk 64], stride 68
    __shared__ __align__(16) bf16 Vs[2][64 * 132];   // V^T [dk 64][kv 128], stride 132
    __shared__ __align__(16) bf16 Ps[128 * 132];     // P [q 128][kv 128], stride 132
    const int tid = threadIdx.x;
    const int w = tid >> 6, l = tid & 63;
    const int l15 = l & 15, l4 = l >> 4;
    const int lin = blockIdx.x;                 // 512 = 8 XCD x 64
    const int swz = (lin & 7) * 64 + (lin >> 3);
    const int bh = swz >> 4;
    const int q0 = (swz & 15) * 128;
    const int b = bh >> 4, h = bh & 15;
    const size_t head = (size_t)bh * SEQ * DK;

    const int ck0 = tid, ck1 = 512 + tid;
    const int kR0 = ck0 >> 3, kS0 = ck0 & 7;
    const int kR1 = ck1 >> 3, kS1 = ck1 & 7;
    const int vR0 = ck0 >> 4, vS0 = ck0 & 15;
    const int vR1 = ck1 >> 4, vS1 = ck1 & 15;

    const int* mrow = mask + b * SEQ;

    short8 aq[2];
#pragma unroll
    for (int ks = 0; ks < 2; ks++)
        aq[ks] = *reinterpret_cast<const short8*>(
            &Qh[head + (size_t)(q0 + w * 16 + l15) * DK + ks * 32 + l4 * 8]);

    {
        short8 k0v = *reinterpret_cast<const short8*>(&Kh[head + (size_t)kR0 * DK + kS0 * 8]);
        short8 k1v = *reinterpret_cast<const short8*>(&Kh[head + (size_t)kR1 * DK + kS1 * 8]);
        short8 v0v = *reinterpret_cast<const short8*>(&Vt[head + (size_t)vR0 * SEQ + vS0 * 8]);
        short8 v1v = *reinterpret_cast<const short8*>(&Vt[head + (size_t)vR1 * SEQ + vS1 * 8]);
        *reinterpret_cast<short8*>(&Ks[0][kR0 * 68 + kS0 * 8]) = k0v;
        *reinterpret_cast<short8*>(&Ks[0][kR1 * 68 + kS1 * 8]) = k1v;
        *reinterpret_cast<short8*>(&Vs[0][vR0 * 132 + vS0 * 8]) = v0v;
        *reinterpret_cast<short8*>(&Vs[0][vR1 * 132 + vS1 * 8]) = v1v;
    }
    __syncthreads();

    f32x4 oacc[4] = {};
    float mrun[4], lrun[4];
#pragma unroll
    for (int j = 0; j < 4; j++) { mrun[j] = -INFINITY; lrun[j] = 0.f; }

    int cur = 0;
    for (int t = 0; t < SEQ / 128; t++) {
        const int kv0 = t * 128;
        const bool more = t < (SEQ / 128 - 1);
        short8 nk0, nk1, nv0, nv1;
        if (more) {
            nk0 = *reinterpret_cast<const short8*>(&Kh[head + (size_t)(kv0 + 128 + kR0) * DK + kS0 * 8]);
            nk1 = *reinterpret_cast<const short8*>(&Kh[head + (size_t)(kv0 + 128 + kR1) * DK + kS1 * 8]);
            nv0 = *reinterpret_cast<const short8*>(&Vt[head + (size_t)vR0 * SEQ + kv0 + 128 + vS0 * 8]);
            nv1 = *reinterpret_cast<const short8*>(&Vt[head + (size_t)vR1 * SEQ + kv0 + 128 + vS1 * 8]);
        }

        // S = Q K^T
        f32x4 sacc[8] = {};
#pragma unroll
        for (int ks = 0; ks < 2; ks++) {
#pragma unroll
            for (int ni = 0; ni < 8; ni++) {
                short8 bk = *reinterpret_cast<const short8*>(
                    &Ks[cur][(ni * 16 + l15) * 68 + ks * 32 + l4 * 8]);
                sacc[ni] = __builtin_amdgcn_mfma_f32_16x16x32_bf16(aq[ks], bk, sacc[ni], 0, 0, 0);
            }
        }

        // mask (L1-hot)
#pragma unroll
        for (int ni = 0; ni < 8; ni++) {
            int mk = mrow[kv0 + ni * 16 + l15];
            if (mk == 0) {
#pragma unroll
                for (int j = 0; j < 4; j++) sacc[ni][j] = NEG_INF_F;
            }
        }

        // masked raw scores -> d_out (512B burst per row per iter)
        {
            size_t base = ((size_t)bh * SEQ + q0 + w * 16) * SEQ + kv0;
#pragma unroll
            for (int j = 0; j < 4; j++) {
                size_t rb = base + (size_t)(l4 * 4 + j) * SEQ;
#pragma unroll
                for (int ni = 0; ni < 8; ni++)
                    __builtin_nontemporal_store(sacc[ni][j], &scores[rb + ni * 16 + l15]);
            }
        }

        // online softmax; rescale only when row max grows; sum deferred
#pragma unroll
        for (int j = 0; j < 4; j++) {
            float mx = fmaxf(fmaxf(fmaxf(sacc[0][j], sacc[1][j]), fmaxf(sacc[2][j], sacc[3][j])),
                             fmaxf(fmaxf(sacc[4][j], sacc[5][j]), fmaxf(sacc[6][j], sacc[7][j])));
#pragma unroll
            for (int d = 1; d < 16; d <<= 1) mx = fmaxf(mx, __shfl_xor(mx, d));
            if (mx > mrun[j]) {
                float fac = __expf(mrun[j] - mx);
                lrun[j] *= fac;
#pragma unroll
                for (int ni = 0; ni < 4; ni++) oacc[ni][j] *= fac;
                mrun[j] = mx;
            }
            float mcur = mrun[j];
            float ps = 0.f;
#pragma unroll
            for (int ni = 0; ni < 8; ni++) {
                float p = __expf(sacc[ni][j] - mcur);
                sacc[ni][j] = p;
                ps += p;
            }
            lrun[j] += ps;
        }

        // P -> LDS (wave-local rows w*16..w*16+15)
#pragma unroll
        for (int j = 0; j < 4; j++) {
            int r = w * 16 + l4 * 4 + j;
#pragma unroll
            for (int ni = 0; ni < 8; ni++)
                Ps[r * 132 + ni * 16 + l15] = __float2bfloat16(sacc[ni][j]);
        }

        // O += P V
#pragma unroll
        for (int ks = 0; ks < 4; ks++) {
            short8 pa = *reinterpret_cast<const short8*>(
                &Ps[(w * 16 + l15) * 132 + ks * 32 + l4 * 8]);
#pragma unroll
            for (int ni = 0; ni < 4; ni++) {
                short8 vbf = *reinterpret_cast<const short8*>(
                    &Vs[cur][(ni * 16 + l15) * 132 + ks * 32 + l4 * 8]);
                oacc[ni] = __builtin_amdgcn_mfma_f32_16x16x32_bf16(pa, vbf, oacc[ni], 0, 0, 0);
            }
        }

        if (more) {
            *reinterpret_cast<short8*>(&Ks[cur ^ 1][kR0 * 68 + kS0 * 8]) = nk0;
            *reinterpret_cast<short8*>(&Ks[cur ^ 1][kR1 * 68 + kS1 * 8]) = nk1;
            *reinterpret_cast<short8*>(&Vs[cur ^ 1][vR0 * 132 + vS0 * 8]) = nv0;
            *reinterpret_cast<short8*>(&Vs[cur ^ 1][vR1 * 132 + vS1 * 8]) = nv1;
        }
        __syncthreads();
        cur ^= 1;
    }

    // epilogue
#pragma unroll
    for (int j = 0; j < 4; j++) {
        float ls = lrun[j];
#pragma unroll
        for (int d = 1; d < 16; d <<= 1) ls += __shfl_xor(ls, d);
        float inv = 1.f / ls;
        int s = q0 + w * 16 + l4 * 4 + j;
#pragma unroll
        for (int ni = 0; ni < 4; ni++)
            attn_c[((size_t)(b * SEQ + s)) * DIM + h * DK + ni * 16 + l15] =
                __float2bfloat16(oacc[ni][j] * inv);
    }
}

extern "C" void kernel_launch(void* const* d_in, const int* in_sizes, int n_in,
                              void* d_out, int out_size, void* d_ws, size_t ws_size,
                              hipStream_t stream)
{
    const float* q  = (const float*)d_in[0];
    const float* k  = (const float*)d_in[1];
    const float* v  = (const float*)d_in[2];
    const int*  msk = (const int*)d_in[3];
    const float* Wq = (const float*)d_in[4];
    const float* bq = (const float*)d_in[5];
    const float* Wk = (const float*)d_in[6];
    const float* bk = (const float*)d_in[7];
    const float* Wv = (const float*)d_in[8];
    const float* bv = (const float*)d_in[9];
    const float* Wo = (const float*)d_in[10];
    const float* bo = (const float*)d_in[11];

    const size_t MB = 1ull << 20;
    char* ws = (char*)d_ws;
    bf16* qb  = (bf16*)(ws + 0 * MB);
    bf16* kb  = (bf16*)(ws + 8 * MB);
    bf16* vb  = (bf16*)(ws + 16 * MB);
    bf16* Wqt = (bf16*)(ws + 24 * MB);
    bf16* Wkt = (bf16*)(ws + 26 * MB);
    bf16* Wvt = (bf16*)(ws + 28 * MB);
    bf16* Wot = (bf16*)(ws + 30 * MB);
    bf16* QhD = (bf16*)(ws + 32 * MB);
    bf16* KhD = (bf16*)(ws + 40 * MB);
    bf16* VtD = (bf16*)(ws + 48 * MB);
    bf16* att = (bf16*)(ws + 56 * MB);

    float* out = (float*)d_out;
    float* scores = out + (size_t)4096 * 1024;

    prep_kernel<<<16384, 256, 0, stream>>>(q, k, v, qb, kb, vb,
                                           Wq, Wk, Wv, Wo, Wqt, Wkt, Wvt, Wot);

    qkv_gemm_kernel<<<768, 256, 0, stream>>>(qb, kb, vb, Wqt, bq, bk, bv, QhD, KhD, VtD);

    attn_kernel<<<512, 512, 0, stream>>>(QhD, KhD, VtD, msk, scores, att);

    o_gemm_kernel<<<512, 256, 0, stream>>>(att, Wot, bo, out);
}